// Round 1
// 411.430 us; speedup vs baseline: 1.0106x; 1.0106x over previous
//
#include <hip/hip_runtime.h>
#include <hip/hip_fp16.h>
#include <math.h>

#define HW 65536            // 256*256
#define CHW 4194304         // 64*HW  (NHWC elements per batch)
#define BCHW 16777216
#define HW2 262144          // 512*512
#define TS 325              // tile pad stride (px) to break LDS conflicts

typedef _Float16 half8 __attribute__((ext_vector_type(8)));
typedef float f32x4 __attribute__((ext_vector_type(4)));

// XCD-aware tile swizzle: ids congruent mod 8 (same XCD under round-robin
// dispatch) map to a contiguous 2-tile-row band. Bijection on 16x16.
__device__ __forceinline__ void swz16(int ibx, int iby, int& ox, int& oy) {
    const int f = ibx + (iby << 4);
    const int k = f & 7, g = f >> 3;
    const int T = (k << 5) + g;
    ox = T & 15; oy = T >> 4;
}

// ---------------------------------------------------------------- ternarize (+ chans zeroing in block 21)
struct TernDesc { const float* src; float* dst; int n; };
struct TernArgs { TernDesc d[21]; };

__global__ __launch_bounds__(256) void ternarize_kernel(TernArgs args, float* __restrict__ chans) {
    const int t = threadIdx.x;
    if (blockIdx.x == 21) {
        for (int i = t; i < 2048; i += 256) chans[i] = 0.f;
        return;
    }
    __shared__ float red[256];
    __shared__ float bc[2];
    TernDesc td = args.d[blockIdx.x];
    const int n = td.n;
    float s = 0.f;
    for (int i = t; i < n; i += 256) s += fabsf(td.src[i]);
    red[t] = s; __syncthreads();
    for (int k = 128; k > 0; k >>= 1) { if (t < k) red[t] += red[t + k]; __syncthreads(); }
    if (t == 0) bc[0] = 0.75f * red[0] / (float)n;
    __syncthreads();
    const float delta = bc[0];
    float s1 = 0.f, c1 = 0.f;
    for (int i = t; i < n; i += 256) {
        float a = fabsf(td.src[i]);
        if (a > delta) { s1 += a; c1 += 1.f; }
    }
    __syncthreads();
    red[t] = s1; __syncthreads();
    for (int k = 128; k > 0; k >>= 1) { if (t < k) red[t] += red[t + k]; __syncthreads(); }
    float sum1 = red[0];
    __syncthreads();
    red[t] = c1; __syncthreads();
    for (int k = 128; k > 0; k >>= 1) { if (t < k) red[t] += red[t + k]; __syncthreads(); }
    if (t == 0) bc[1] = sum1 / fmaxf(red[0], 1.f);
    __syncthreads();
    const float alpha = bc[1];
    for (int i = t; i < n; i += 256) {
        float w = td.src[i];
        td.dst[i] = (fabsf(w) > delta) ? ((w > 0.f) ? alpha : -alpha) : 0.f;
    }
}

// ---------------------------------------------------------------- fused shallow conv + texture encoder + router (512 thr)
__global__ __launch_bounds__(512, 6) void shallow_router_kernel(
    const float* __restrict__ x,
    const float* __restrict__ qsh,  const float* __restrict__ shb,
    const float* __restrict__ qtdw, const float* __restrict__ tdwb,
    const float* __restrict__ qtpw, const float* __restrict__ tpwb,
    const float* __restrict__ rw,   const float* __restrict__ rbias,
    __half* __restrict__ feat_h, int* __restrict__ top) {
    __shared__ float xs[1200];          // [3][20][20]
    __shared__ float feats[324 * 33];   // [halo px][ch pad33]
    const int t = threadIdx.x;
    const int b = blockIdx.z;
    const int h0 = blockIdx.y * 16, w0 = blockIdx.x * 16;
    const float* xb = x + (size_t)b * 3 * HW;

    for (int i = t; i < 1200; i += 512) {
        const int ci = i / 400, rem = i - ci * 400;
        const int ry = rem / 20, rx = rem - ry * 20;
        const int hh = h0 + ry - 2, ww = w0 + rx - 2;
        xs[i] = (hh >= 0 && hh < 256 && ww >= 0 && ww < 256) ? xb[ci * HW + hh * 256 + ww] : 0.f;
    }
    float tex[8] = {0, 0, 0, 0, 0, 0, 0, 0};
    __half* fhb = feat_h + (size_t)b * CHW;
    __syncthreads();

    for (int pass = 0; pass < 2; pass++) {
        const int c0 = pass * 32;
        if (pass) __syncthreads();
        if (t < 324) {
            const int ry = t / 18, rx = t - ry * 18;
            float patch[27];
#pragma unroll
            for (int ci = 0; ci < 3; ci++)
#pragma unroll
                for (int dy = 0; dy < 3; dy++)
#pragma unroll
                    for (int dx = 0; dx < 3; dx++)
                        patch[ci * 9 + dy * 3 + dx] = xs[ci * 400 + (ry + dy) * 20 + rx + dx];
            for (int co = 0; co < 32; co++) {
                const float* wp = &qsh[(c0 + co) * 27];
                float a = shb[c0 + co];
#pragma unroll
                for (int k = 0; k < 27; k++) a = fmaf(patch[k], wp[k], a);
                feats[t * 33 + co] = fmaxf(a, 0.f);
            }
        }
        __syncthreads();
        if (t < 256) {
            const int iy = t >> 4, ix = t & 15;
            for (int ch = 0; ch < 32; ch++) {
                const float* wp = &qtdw[(c0 + ch) * 9];
                float o = tdwb[c0 + ch];
#pragma unroll
                for (int dy = 0; dy < 3; dy++) {
                    const float* rowp = &feats[((iy + dy) * 18 + ix) * 33 + ch];
                    o = fmaf(rowp[0], wp[dy * 3],
                        fmaf(rowp[33], wp[dy * 3 + 1],
                            fmaf(rowp[66], wp[dy * 3 + 2], o)));
                }
                const float tc = fmaxf(o, 0.f);
#pragma unroll
                for (int j = 0; j < 8; j++) tex[j] = fmaf(qtpw[j * 64 + c0 + ch], tc, tex[j]);
            }
        } else {
            for (int id = t - 256; id < 1024; id += 256) {
                const int p = id >> 2, cg = id & 3;
                const int py = p >> 4, px = p & 15;
                const float* fp = &feats[((py + 1) * 18 + px + 1) * 33 + cg * 8];
                half8 pk;
#pragma unroll
                for (int j = 0; j < 8; j++) pk[j] = (_Float16)fp[j];
                *(half8*)&fhb[((size_t)((h0 + py) * 256 + w0 + px)) * 64 + c0 + cg * 8] = pk;
            }
        }
    }
    if (t < 256) {
        const int iy = t >> 4, ix = t & 15;
        float sgm[8];
#pragma unroll
        for (int j = 0; j < 8; j++) sgm[j] = 1.f / (1.f + expf(-(tex[j] + tpwb[j])));
        float best = -1e30f; int bi = 0;
#pragma unroll
        for (int e = 0; e < 4; e++) {
            float v = rbias[e];
#pragma unroll
            for (int j = 0; j < 8; j++) v = fmaf(rw[e * 8 + j], sgm[j], v);
            if (v > best) { best = v; bi = e; }     // first max (jnp.argmax)
        }
        top[(size_t)b * HW + (h0 + iy) * 256 + w0 + ix] = bi;
    }
}

// ---------------------------------------------------------------- expert block: 512 threads, ebase-parameterized
// grid z = 4 * nexp; b = z&3, slot/sub = z>>2, expert = ebase + sub.
// APPLY computes its own y0 from chans (identical fmaf order to the old
// y_kernel), masks routed writes via topsm only.
// Depthwise conv is packed fp16 (v_pk_fma_f16): data is fp16 in LDS and the
// consumer (MFMA A-operand) is fp16 -- f32 round-trip was 4x the VALU instrs.
template <bool APPLY>
__global__ __launch_bounds__(512, 4) void expert_block_kernel(
    const __half* __restrict__ in,
    const float* __restrict__ qdw_b, const float* __restrict__ dwb_b,
    const float* __restrict__ qpw_b, const float* __restrict__ pwb_b,
    __half* __restrict__ out_b, float* __restrict__ chans_b,
    const float* __restrict__ fc1b, const float* __restrict__ fc2b,
    const __half* __restrict__ F, __half* __restrict__ Aap,
    const int* __restrict__ topg, int ebase) {
    __shared__ __half tile[8 * TS * 8];    // 41600 B; obuf + csb alias after compute
    __shared__ __half wT[64 * 72];         // [co][ci pad72] 9216 B
    __shared__ __half wdwh[9 * 64];        // [tap][ci] 1152 B
    __shared__ __align__(16) _Float16 bdwh[64];
    __shared__ float bpw[64];
    __shared__ unsigned char topsm[256];
    __shared__ float hid0[16];
    __shared__ __align__(16) _Float16 ysm0h[64];
    const int t = threadIdx.x;
    const int z = blockIdx.z;
    const int b = z & 3, sub = z >> 2;
    const int expert = ebase + sub;
    const int layer = expert * 2 + (APPLY ? 1 : 0);
    const float* qdw = qdw_b + layer * 576;
    const float* dwb = dwb_b + layer * 64;
    const float* qpw = qpw_b + layer * 4096;
    const float* pwb = pwb_b + layer * 64;
    float* chansum = chans_b + layer * 256;
    int bx, by; swz16(blockIdx.x, blockIdx.y, bx, by);
    const int h0 = by * 16, w0 = bx * 16;

    for (int i = t; i < 4096; i += 512) wT[(i >> 6) * 72 + (i & 63)] = __float2half(qpw[i]);
    for (int i = t; i < 576; i += 512) {
        const int ci = i / 9, tap = i - ci * 9;
        wdwh[tap * 64 + ci] = __float2half(qdw[i]);
    }
    if (t < 64) { bdwh[t] = (_Float16)dwb[t]; bpw[t] = pwb[t]; }

    half8 y8h = {};
    if (APPLY) {
        if (t < 256)
            topsm[t] = (unsigned char)topg[(size_t)b * HW + (h0 + (t >> 4)) * 256 + w0 + (t & 15)];
        if (t < 16) {   // y0 stage 1 (same fmaf order as old y_kernel)
            const float* fc1 = fc1b + (expert * 2) * 1024;
            const float* cs = chans_b + (expert * 2) * 256 + b * 64;
            float s = 0.f;
            for (int ci = 0; ci < 64; ci++) s = fmaf(fc1[t * 64 + ci], cs[ci], s);
            hid0[t] = fmaxf(s, 0.f) * (1.f / 65536.f);
        }
        __syncthreads();
        if (t < 64) {   // y0 stage 2
            const float* fc2 = fc2b + (expert * 2) * 1024;
            float s = 0.f;
#pragma unroll
            for (int j = 0; j < 16; j++) s = fmaf(fc2[t * 16 + j], hid0[j], s);
            ysm0h[t] = (_Float16)(1.f / (1.f + expf(-s)));
        }
        __syncthreads();
        const int scg = t & 7;
        y8h = *(const half8*)&ysm0h[scg * 8];
    }

    const __half* ib = (APPLY ? in + (size_t)sub * BCHW : in) + (size_t)b * CHW;
    const __half* Fb = APPLY ? (F + (size_t)b * CHW) : nullptr;
    __half* Ab = APPLY ? (Aap + (size_t)b * CHW) : nullptr;
    __half* ob = APPLY ? (out_b + (size_t)b * CHW)
                       : (out_b + (size_t)sub * BCHW + (size_t)b * CHW);

    // staging, force-unrolled: 5 full iterations + 32-thread tail
#pragma unroll
    for (int s = 0; s < 6; s++) {
        if (s < 5 || t < 32) {
            const int i = t + (s << 9);
            const int cg = i & 7;
            const int rem = i >> 3;            // 0..323
            const int ry = rem / 18, rx = rem - ry * 18;
            const int hh = h0 + ry - 1, ww = w0 + rx - 1;
            half8 v = {};
            if (hh >= 0 && hh < 256 && ww >= 0 && ww < 256) {
                const size_t off = (size_t)(hh * 256 + ww) * 64 + cg * 8;
                v = *(const half8*)&ib[off];
                if (APPLY) {
                    half8 f = *(const half8*)&Fb[off];
                    v = __builtin_elementwise_fma(v, y8h, f);
                    if (ry >= 1 && ry <= 16 && rx >= 1 && rx <= 16 &&
                        topsm[((ry - 1) << 4) + (rx - 1)] == expert)
                        *(half8*)&Ab[off] = v;
                }
            }
            *(half8*)&tile[(cg * TS + rem) * 8] = v;
        }
    }
    __syncthreads();

    const int lane = t & 63, wv = t >> 6;      // 8 waves, 2 rows each
    const int l15 = lane & 15, quad = lane >> 4;
    f32x4 acc[2][4];
#pragma unroll
    for (int i = 0; i < 2; i++)
#pragma unroll
        for (int j = 0; j < 4; j++) acc[i][j] = (f32x4){0.f, 0.f, 0.f, 0.f};

#pragma unroll
    for (int kh = 0; kh < 2; kh++) {
        const int cgk = kh * 4 + quad;
        half8 bf[4];
#pragma unroll
        for (int ct = 0; ct < 4; ct++)
            bf[ct] = *(const half8*)&wT[(ct * 16 + l15) * 72 + kh * 32 + quad * 8];
        half8 wv9[9];
#pragma unroll
        for (int tap = 0; tap < 9; tap++)
            wv9[tap] = *(const half8*)&wdwh[tap * 64 + kh * 32 + quad * 8];
        const half8 biash = *(const half8*)&bdwh[kh * 32 + quad * 8];
        // row-shared tap loads: rows wv*2..wv*2+3 (T=0 uses 0..2, T=1 uses 1..3)
        half8 xr[9];
#pragma unroll
        for (int dy = 0; dy < 3; dy++)
#pragma unroll
            for (int dx = 0; dx < 3; dx++)
                xr[dy * 3 + dx] = *(const half8*)&tile[(cgk * TS + (wv * 2 + dy) * 18 + (l15 + dx)) * 8];
#pragma unroll
        for (int T = 0; T < 2; T++) {
            if (T) {
#pragma unroll
                for (int q2 = 0; q2 < 6; q2++) xr[q2] = xr[q2 + 3];
#pragma unroll
                for (int dx = 0; dx < 3; dx++)
                    xr[6 + dx] = *(const half8*)&tile[(cgk * TS + (wv * 2 + 3) * 18 + (l15 + dx)) * 8];
            }
            // packed fp16 depthwise accumulate: 4x v_pk_fma_f16 per tap, no cvts
            half8 o8 = biash;
#pragma unroll
            for (int tap = 0; tap < 9; tap++)
                o8 = __builtin_elementwise_fma(xr[tap], wv9[tap], o8);
            const half8 zz = {};
            const half8 a = __builtin_elementwise_max(o8, zz);
#pragma unroll
            for (int ct = 0; ct < 4; ct++)
                acc[T][ct] = __builtin_amdgcn_mfma_f32_16x16x32_f16(a, bf[ct], acc[T][ct], 0, 0, 0);
        }
    }
    __syncthreads();   // tile reads done; alias obuf + csb onto tile

    __half* obuf = tile;                              // bytes 0..17407
    float* csb = (float*)((char*)tile + 20480);       // [8][64] floats
    __half* myo = &obuf[wv * 1088];
    float cs[4] = {0.f, 0.f, 0.f, 0.f};
    const int pxa = lane >> 3;
#pragma unroll
    for (int T = 0; T < 2; T++) {
        const int py_loc = wv * 2 + T;
#pragma unroll
        for (int ct = 0; ct < 4; ct++) {
            const float bv = bpw[ct * 16 + l15];
#pragma unroll
            for (int r = 0; r < 4; r++) {
                const float v = acc[T][ct][r] + bv;
                cs[ct] += v;
                myo[(quad * 4 + r) * 68 + ct * 16 + l15] = __float2half(v);
            }
        }
        const int py = h0 + py_loc;
        const size_t base = (size_t)(py * 256 + w0) * 64;
        half8 v0 = *(const half8*)&myo[pxa * 68 + (lane & 7) * 8];
        half8 v1 = *(const half8*)&myo[(8 + pxa) * 68 + (lane & 7) * 8];
        if (!APPLY || topsm[py_loc * 16 + pxa] == expert)
            *(half8*)&ob[base + lane * 8] = v0;
        if (!APPLY || topsm[py_loc * 16 + 8 + pxa] == expert)
            *(half8*)&ob[base + (lane + 64) * 8] = v1;
    }
#pragma unroll
    for (int ct = 0; ct < 4; ct++) {
        float s = cs[ct];
        s += __shfl_xor(s, 16);
        s += __shfl_xor(s, 32);
        if (quad == 0) csb[wv * 64 + ct * 16 + l15] = s;
    }
    __syncthreads();
    if (t < 64) {
        float s = 0.f;
#pragma unroll
        for (int w = 0; w < 8; w++) s += csb[w * 64 + t];
        atomicAdd(&chansum[b * 64 + t], s);
    }
}

// ---------------------------------------------------------------- bilinear x2 upsample (jax.image.resize semantics)
__device__ __forceinline__ float bilin_up(const float* __restrict__ xb, int h, int w, int r1, int r2) {
    int hlo, hhi; float wrr;
    if (r1 == 0) { hlo = h - 1; hhi = h;     wrr = 0.25f; }
    else         { hlo = h;     hhi = h + 1; wrr = 0.75f; }
    if (hlo < 0)   { hlo = 0;   wrr = 0.f; }
    if (hhi > 255) { hhi = 255; wrr = 1.f; }
    int wlo, whi; float wcc;
    if (r2 == 0) { wlo = w - 1; whi = w;     wcc = 0.25f; }
    else         { wlo = w;     whi = w + 1; wcc = 0.75f; }
    if (wlo < 0)   { wlo = 0;   wcc = 0.f; }
    if (whi > 255) { whi = 255; wcc = 1.f; }
    const float a = xb[hlo * 256 + wlo] * wcc + xb[hlo * 256 + whi] * (1.f - wcc);
    const float b = xb[hhi * 256 + wlo] * wcc + xb[hhi * 256 + whi] * (1.f - wcc);
    return a * wrr + b * (1.f - wrr);
}

// ---------------------------------------------------------------- recon (512 thr) fused select + in-block y1; fp16 sr out
__global__ __launch_bounds__(512, 4) void recon_kernel(const __half* __restrict__ Bv,
                                                       const __half* __restrict__ Aap,
                                                       const int* __restrict__ topg,
                                                       const float* __restrict__ chans,
                                                       const float* __restrict__ fc1b,
                                                       const float* __restrict__ fc2b,
                                                       const float* __restrict__ rw,   // [12][64][9]
                                                       const float* __restrict__ rbias,
                                                       const float* __restrict__ x,
                                                       __half* __restrict__ srh) {
    __shared__ __half tile[8 * TS * 8];     // 41600 B
    __shared__ __half Wt[9 * 16 * 72];      // 20736 B
    __shared__ float bsm12[12];
    __shared__ __align__(16) _Float16 ysmh[4][64];
    __shared__ float hid[4][16];
    const int t = threadIdx.x;
    const int b = blockIdx.z;
    int bx, by; swz16(blockIdx.x, blockIdx.y, bx, by);
    const int h0 = by * 16, w0 = bx * 16;

    for (int i = t; i < 9216; i += 512) {
        const int tap = i / 1024, rem = i - tap * 1024;
        const int n = rem >> 6, ci = rem & 63;
        Wt[(tap * 16 + n) * 72 + ci] = __float2half(n < 12 ? rw[n * 576 + ci * 9 + tap] : 0.f);
    }
    if (t < 12) bsm12[t] = rbias[t];
    if (t < 64) {   // y1 stage 1 (same fmaf order as old y_kernel)
        const int e = t >> 4, j = t & 15, li = e * 2 + 1;
        const float* fc1 = fc1b + li * 1024;
        const float* cs = chans + li * 256 + b * 64;
        float s = 0.f;
        for (int ci = 0; ci < 64; ci++) s = fmaf(fc1[j * 64 + ci], cs[ci], s);
        hid[e][j] = fmaxf(s, 0.f) * (1.f / 65536.f);
    }
    __syncthreads();
    if (t < 256) {  // y1 stage 2
        const int e = t >> 6, c = t & 63, li = e * 2 + 1;
        const float* fc2 = fc2b + li * 1024;
        float s = 0.f;
#pragma unroll
        for (int j = 0; j < 16; j++) s = fmaf(fc2[c * 16 + j], hid[e][j], s);
        ysmh[e][c] = (_Float16)(1.f / (1.f + expf(-s)));
    }
    __syncthreads();    // ysmh + Wt ready

    const __half* bb = Bv + (size_t)b * CHW;
    const __half* ab = Aap + (size_t)b * CHW;
    const int* tb = topg + (size_t)b * HW;

#pragma unroll
    for (int s = 0; s < 6; s++) {
        if (s < 5 || t < 32) {
            const int i = t + (s << 9);
            const int cg = i & 7;
            const int rem = i >> 3;
            const int ry = rem / 18, rx = rem - ry * 18;
            const int hh = h0 + ry - 1, ww = w0 + rx - 1;
            half8 v = {};
            if (hh >= 0 && hh < 256 && ww >= 0 && ww < 256) {
                const size_t off = (size_t)(hh * 256 + ww) * 64 + cg * 8;
                half8 bv8 = *(const half8*)&bb[off];
                half8 av8 = *(const half8*)&ab[off];
                const int e = tb[hh * 256 + ww];
                half8 yv = *(const half8*)&ysmh[e][cg * 8];
                v = __builtin_elementwise_fma(bv8, yv, av8);
            }
            *(half8*)&tile[(cg * TS + rem) * 8] = v;
        }
    }
    __syncthreads();

    const int lane = t & 63, wvi = t >> 6;
    const int l15 = lane & 15, quad = lane >> 4;
    f32x4 acc[2];
#pragma unroll
    for (int i = 0; i < 2; i++) acc[i] = (f32x4){0.f, 0.f, 0.f, 0.f};

#pragma unroll
    for (int kh = 0; kh < 2; kh++) {
        const int cgk = kh * 4 + quad;
        half8 bf[9];
#pragma unroll
        for (int tap = 0; tap < 9; tap++)
            bf[tap] = *(const half8*)&Wt[(tap * 16 + l15) * 72 + kh * 32 + quad * 8];
        // row-shared tap loads
        half8 xr[9];
#pragma unroll
        for (int dy = 0; dy < 3; dy++)
#pragma unroll
            for (int dx = 0; dx < 3; dx++)
                xr[dy * 3 + dx] = *(const half8*)&tile[(cgk * TS + (wvi * 2 + dy) * 18 + (l15 + dx)) * 8];
#pragma unroll
        for (int T = 0; T < 2; T++) {
            if (T) {
#pragma unroll
                for (int q2 = 0; q2 < 6; q2++) xr[q2] = xr[q2 + 3];
#pragma unroll
                for (int dx = 0; dx < 3; dx++)
                    xr[6 + dx] = *(const half8*)&tile[(cgk * TS + (wvi * 2 + 3) * 18 + (l15 + dx)) * 8];
            }
#pragma unroll
            for (int tap = 0; tap < 9; tap++)
                acc[T] = __builtin_amdgcn_mfma_f32_16x16x32_f16(xr[tap], bf[tap], acc[T], 0, 0, 0);
        }
    }
    if (l15 < 12) {
        const int c = l15 >> 2, r1 = (l15 >> 1) & 1, r2 = l15 & 1;
        const float* xb = x + ((size_t)b * 3 + c) * HW;
        const float bv = bsm12[l15];
        __half* sb = srh + ((size_t)b * 3 + c) * HW2;
#pragma unroll
        for (int T = 0; T < 2; T++) {
            const int py = h0 + wvi * 2 + T;
#pragma unroll
            for (int r = 0; r < 4; r++) {
                const int wglob = w0 + quad * 4 + r;
                const float xu = bilin_up(xb, py, wglob, r1, r2);
                sb[(2 * py + r1) * 512 + 2 * wglob + r2] = __float2half(acc[T][r] + bv + xu);
            }
        }
    }
}

// ---------------------------------------------------------------- fused refinement: out = sr + conv2(relu(conv1(sr))); fp16 sr in
__global__ __launch_bounds__(256) void ref_fused_kernel(const __half* __restrict__ in,  // sr half [4][3][512][512]
                                                        const float* __restrict__ q1,
                                                        const float* __restrict__ b1,
                                                        const float* __restrict__ q2,
                                                        const float* __restrict__ b2,
                                                        float* __restrict__ outp) {
    __shared__ float srs[1200];       // [3][20][20] halo ±2
    __shared__ float t1s[3 * 324];    // [3][18][18] halo ±1
    __shared__ float w1[81], w2[81];
    __shared__ float bb1[3], bb2[3];
    const int t = threadIdx.y * 16 + threadIdx.x;
    const int b = blockIdx.z;
    const int h0 = blockIdx.y * 16, w0 = blockIdx.x * 16;
    if (t < 81) { w1[t] = q1[t]; w2[t] = q2[t]; }
    if (t < 3)  { bb1[t] = b1[t]; bb2[t] = b2[t]; }
    for (int i = t; i < 1200; i += 256) {
        const int ci = i / 400, rem = i - ci * 400;
        const int ry = rem / 20, rx = rem - ry * 20;
        const int hh = h0 + ry - 2, ww = w0 + rx - 2;
        srs[i] = (hh >= 0 && hh < 512 && ww >= 0 && ww < 512)
                   ? __half2float(in[((size_t)b * 3 + ci) * HW2 + hh * 512 + ww]) : 0.f;
    }
    __syncthreads();
    for (int p = t; p < 324; p += 256) {
        const int ry = p / 18, rx = p - ry * 18;
        const int ih = h0 + ry - 1, iw = w0 + rx - 1;
        const bool valid = (ih >= 0 && ih < 512 && iw >= 0 && iw < 512);
#pragma unroll
        for (int o = 0; o < 3; o++) {
            float a = 0.f;
#pragma unroll
            for (int ci = 0; ci < 3; ci++) {
                const float* wp = &w1[o * 27 + ci * 9];
                const float* sp = &srs[ci * 400 + ry * 20 + rx];
#pragma unroll
                for (int ky = 0; ky < 3; ky++)
#pragma unroll
                    for (int kx = 0; kx < 3; kx++)
                        a = fmaf(sp[ky * 20 + kx], wp[ky * 3 + kx], a);
            }
            t1s[o * 324 + p] = valid ? fmaxf(a + bb1[o], 0.f) : 0.f;
        }
    }
    __syncthreads();
    const int ty = threadIdx.y, tx = threadIdx.x;
#pragma unroll
    for (int o = 0; o < 3; o++) {
        float a = 0.f;
#pragma unroll
        for (int ci = 0; ci < 3; ci++) {
            const float* wp = &w2[o * 27 + ci * 9];
            const float* tp = &t1s[ci * 324 + ty * 18 + tx];
#pragma unroll
            for (int ky = 0; ky < 3; ky++)
#pragma unroll
                for (int kx = 0; kx < 3; kx++)
                    a = fmaf(tp[ky * 18 + kx], wp[ky * 3 + kx], a);
        }
        const float v = a + bb2[o] + srs[o * 400 + (ty + 2) * 20 + tx + 2];
        outp[((size_t)b * 3 + o) * HW2 + (h0 + ty) * 512 + w0 + tx] = v;
    }
}

// ---------------------------------------------------------------- launcher
extern "C" void kernel_launch(void* const* d_in, const int* in_sizes, int n_in,
                              void* d_out, int out_size, void* d_ws, size_t ws_size,
                              hipStream_t stream) {
    const float* x         = (const float*)d_in[0];
    const float* shallow_w = (const float*)d_in[1];
    const float* shallow_b = (const float*)d_in[2];
    const float* tex_dw_w  = (const float*)d_in[3];
    const float* tex_dw_b  = (const float*)d_in[4];
    const float* tex_pw_w  = (const float*)d_in[5];
    const float* tex_pw_b  = (const float*)d_in[6];
    const float* router_w  = (const float*)d_in[7];
    const float* router_b  = (const float*)d_in[8];
    const float* exp_dw_w  = (const float*)d_in[9];
    const float* exp_dw_b  = (const float*)d_in[10];
    const float* exp_pw_w  = (const float*)d_in[11];
    const float* exp_pw_b  = (const float*)d_in[12];
    const float* exp_fc1   = (const float*)d_in[13];
    const float* exp_fc2   = (const float*)d_in[14];
    const float* recon_w   = (const float*)d_in[15];
    const float* recon_b   = (const float*)d_in[16];
    const float* ref1_w    = (const float*)d_in[17];
    const float* ref1_b    = (const float*)d_in[18];
    const float* ref2_w    = (const float*)d_in[19];
    const float* ref2_b    = (const float*)d_in[20];

    // mode: merged (all 4 experts per dispatch, 4 A-slots) if workspace allows
    const size_t need_merged = 237000000ULL;
    const bool merged = (ws_size >= need_merged);
    const int nslot = merged ? 4 : 2;

    __half* feat_h = (__half*)d_ws;                      // 32 MB
    __half* A4     = feat_h + BCHW;                      // nslot x 32 MB
    __half* Bv_sh  = A4 + (size_t)nslot * BCHW;          // 32 MB, routed-shared
    __half* Aap_sh = Bv_sh + BCHW;                       // 32 MB, routed-shared
    int*    top    = (int*)(Aap_sh + BCHW);              // 1 MB
    float*  qb     = (float*)(top + 262144);
    float*  q_sh   = qb;                 // 1728
    float*  q_tdw  = q_sh + 1728;        // 576
    float*  q_tpw  = q_tdw + 576;        // 512
    float*  q_edw  = q_tpw + 512;        // 8*576
    float*  q_epw  = q_edw + 4608;       // 8*4096
    float*  q_r1   = q_epw + 32768;      // 81
    float*  q_r2   = q_r1 + 81;          // 81
    float*  chans  = q_r2 + 81;          // 8*256
    __half* srh    = (__half*)A4;        // 25 MB as half (A4 dead after last APPLY)

    TernArgs ta;
    ta.d[0] = { shallow_w, q_sh, 1728 };
    ta.d[1] = { tex_dw_w, q_tdw, 576 };
    ta.d[2] = { tex_pw_w, q_tpw, 512 };
    for (int i = 0; i < 8; i++) ta.d[3 + i]  = { exp_dw_w + i * 576,  q_edw + i * 576,  576 };
    for (int i = 0; i < 8; i++) ta.d[11 + i] = { exp_pw_w + i * 4096, q_epw + i * 4096, 4096 };
    ta.d[19] = { ref1_w, q_r1, 81 };
    ta.d[20] = { ref2_w, q_r2, 81 };
    ternarize_kernel<<<22, 256, 0, stream>>>(ta, chans);   // block 21 zeroes chans

    shallow_router_kernel<<<dim3(16, 16, 4), 512, 0, stream>>>(
        x, q_sh, shallow_b, q_tdw, tex_dw_b, q_tpw, tex_pw_b, router_w, router_b,
        feat_h, top);

    if (merged) {
        expert_block_kernel<false><<<dim3(16, 16, 16), 512, 0, stream>>>(
            feat_h, q_edw, exp_dw_b, q_epw, exp_pw_b,
            A4, chans, nullptr, nullptr, nullptr, nullptr, nullptr, 0);
        expert_block_kernel<true><<<dim3(16, 16, 16), 512, 0, stream>>>(
            A4, q_edw, exp_dw_b, q_epw, exp_pw_b,
            Bv_sh, chans, exp_fc1, exp_fc2, feat_h, Aap_sh, top, 0);
    } else {
        for (int s = 0; s < 2; s++) {
            expert_block_kernel<false><<<dim3(16, 16, 8), 512, 0, stream>>>(
                feat_h, q_edw, exp_dw_b, q_epw, exp_pw_b,
                A4, chans, nullptr, nullptr, nullptr, nullptr, nullptr, s * 2);
            expert_block_kernel<true><<<dim3(16, 16, 8), 512, 0, stream>>>(
                A4, q_edw, exp_dw_b, q_epw, exp_pw_b,
                Bv_sh, chans, exp_fc1, exp_fc2, feat_h, Aap_sh, top, s * 2);
        }
    }

    recon_kernel<<<dim3(16, 16, 4), 512, 0, stream>>>(Bv_sh, Aap_sh, top,
                                                      chans, exp_fc1, exp_fc2,
                                                      recon_w, recon_b, x, srh);
    ref_fused_kernel<<<dim3(32, 32, 4), dim3(16, 16), 0, stream>>>(
        srh, q_r1, ref1_b, q_r2, ref2_b, (float*)d_out);
}